// Round 7
// baseline (229.086 us; speedup 1.0000x reference)
//
#include <hip/hip_runtime.h>

// CIN_51539607712 — R7: factorized MFMA, 32-row waves (no per-iter A-pack).
// out[r,n] = sum_h xl[r,h]*Y_h[r,n],  Y_h[r,n] = sum_m x0[r,m] W[h*32+m,n].
// A-operand = x0 splits: LOOP-INVARIANT pre-packed bf16 frags (packed once).
// Per h: Y = 6 chained MFMAs (2 sub-k x 3 split terms), then fp32 fold
// acc[i] += xl[row(i)] * Y[i]  (xl untruncated -> same accuracy as R6).
// Block = 64 rows x 64 cols, 512 thr = 8 waves: rt = w>>2 (row-tile of 32),
// kq = (w>>1)&1 (K-half), nh = w&1 (N-32-half). Grid = 512 (rb, ch).
// Per-wave PRIVATE 2-deep 2KB staging ring (global_load_lds w=16), barrier-
// free K-loop (per-wave vmcnt(0)). LDS = 32 KB -> 2 blocks/CU = 4 waves/SIMD.
// NOTE: __launch_bounds__ arg2 = min BLOCKS/CU on this toolchain (R4 evidence).
// Cost accepted: 32-row tiles double W L2 traffic (1 GB/big layer) — may soft-
// bound at ~29 us/layer; registers are the scarcer resource (R5 post-mortem).

typedef unsigned int u32;
typedef __attribute__((ext_vector_type(8))) short short8;
typedef __attribute__((ext_vector_type(4))) float f32x4;
typedef __attribute__((ext_vector_type(16))) float f32x16;
typedef __attribute__((ext_vector_type(4))) u32 u32x4;

#define R_TOTAL 16384
#define GLOBAL_AS __attribute__((address_space(1)))
#define LDS_AS __attribute__((address_space(3)))

union PackU { u32 u[4]; short8 s; };
union PackB { u32x4 v; short8 s; };

__device__ __forceinline__ u32 pack_trunc(float a, float b) {
  return __builtin_amdgcn_perm(__float_as_uint(b), __float_as_uint(a), 0x07060302u);
}

// ---------------- prep: X0T[m][b*16+d] = in[b][m][d]  (32 x 16384) ----------
__global__ __launch_bounds__(256) void build_x0t(const float* __restrict__ in,
                                                 float* __restrict__ x0t) {
  __shared__ float t[4096];
  const int tid = threadIdx.x;
  const int b0 = blockIdx.x * 8;
  #pragma unroll
  for (int rep = 0; rep < 4; ++rep) {
    int idx = tid + rep * 256;
    *(float4*)&t[idx * 4] = *(const float4*)&in[(size_t)b0 * 512 + idx * 4];
  }
  __syncthreads();
  #pragma unroll
  for (int rep = 0; rep < 4; ++rep) {
    int idx = tid + rep * 256;     // 0..1023: m(32) x bl(8) x dq(4)
    int m = idx >> 5, rem = idx & 31;
    int bl = rem >> 2, dq = rem & 3;
    *(float4*)&x0t[(size_t)m * R_TOTAL + (b0 + bl) * 16 + dq * 4] =
        *(const float4*)&t[bl * 512 + m * 16 + dq * 4];
  }
}

// ---------------- prep: split+pack W into 2 KB sub-k units -------------------
// Unit (h, nq, s) at u32-offset ((h*4+nq)*2+s)*512. Entry e = p*64+q2*32+n
// (16 B): bf16 pairs (k=2r,2r+1) of part p of W[h*32+s*16+q2*8+(0..7)][nq*32+n].
__global__ __launch_bounds__(256) void swizzle_w(const float* __restrict__ W,
                                                 u32* __restrict__ wt) {
  __shared__ float wl[32 * 132];
  const int tid = threadIdx.x;
  const int h = blockIdx.x;
  #pragma unroll
  for (int rep = 0; rep < 4; ++rep) {
    int idx = tid + rep * 256;          // 1024 float4 = 32 k x 32 f4
    int kk = idx >> 5, c4 = idx & 31;
    *(float4*)&wl[kk * 132 + c4 * 4] =
        *(const float4*)&W[(size_t)(h * 32 + kk) * 128 + c4 * 4];
  }
  __syncthreads();
  #pragma unroll
  for (int rep = 0; rep < 4; ++rep) {
    int e = tid + rep * 256;            // 1024 entries (4 nq x 2 s x 128)
    int nq = e >> 8, rem = e & 255;
    int s = rem >> 7, p = (rem >> 6) & 1, q2 = (rem >> 5) & 1, n = rem & 31;
    int k0 = s * 16 + q2 * 8, col = nq * 32 + n;
    u32 o[4];
    #pragma unroll
    for (int r = 0; r < 4; ++r) {
      float v0 = wl[(k0 + 2 * r) * 132 + col];
      float v1 = wl[(k0 + 2 * r + 1) * 132 + col];
      if (p == 1) {
        v0 -= __uint_as_float(__float_as_uint(v0) & 0xffff0000u);
        v1 -= __uint_as_float(__float_as_uint(v1) & 0xffff0000u);
      }
      o[r] = pack_trunc(v0, v1);
    }
    *(u32x4*)(wt + (((size_t)h * 4 + nq) * 2 + s) * 512 + (rem & 127) * 4) =
        u32x4{o[0], o[1], o[2], o[3]};
  }
}

// ---------------- per-wave sub-k staging: 2048 B via global_load_lds ---------
__device__ __forceinline__ void stage2k(const u32* g, u32* l, int lane) {
  const GLOBAL_AS u32* gp = (const GLOBAL_AS u32*)g;
  LDS_AS u32* lp = (LDS_AS u32*)l;
  __builtin_amdgcn_global_load_lds(gp + lane * 4, lp, 16, 0, 0);
  __builtin_amdgcn_global_load_lds(gp + 256 + lane * 4, lp + 256, 16, 0, 0);
}

// ---------------- main layer kernel ----------------
template <int NT, bool RELU, bool STORE_X>
__global__ __launch_bounds__(512, 2) void layer_mfma(
    const float* __restrict__ xt,    // NT x R (transposed prev activation)
    const float* __restrict__ x0t,   // 32 x R
    const u32* __restrict__ wt,      // NT*8 sub-k units (512 u32 each)
    const float* __restrict__ bias,  // 128
    float* __restrict__ xoutT,       // 128 x R (if STORE_X)
    float* __restrict__ osum)        // d_out + layer offset, stride 384
{
  constexpr int HKW = NT / 2;         // h-values per wave (K-half)
  __shared__ u32 smem[8192];          // 32 KB: 8 waves x 1024 u32 (2x2KB ring)

  const int tid = threadIdx.x;
  const int w = tid >> 6, lane = tid & 63;
  const int rt = w >> 2, kq = (w >> 1) & 1, nh = w & 1;
  const int ln31 = lane & 31, q2 = lane >> 5;
  const int rb = blockIdx.x >> 1, ch = blockIdx.x & 1;
  const int nq = ch * 2 + nh;         // global col-quarter 0..3
  const int r0 = rb * 64;
  const int rbase = r0 + rt * 32;     // this wave's 32-row tile
  u32* mybuf = smem + w * 1024;

  // ---- loop-invariant A-frags: x0 splits, A[m=ln31][k=q2*8+j], sub-k s ----
  PackU Ah[2], Al[2];
  #pragma unroll
  for (int s = 0; s < 2; ++s) {
    #pragma unroll
    for (int r = 0; r < 4; ++r) {
      float v0 = x0t[(size_t)(s * 16 + q2 * 8 + 2 * r + 0) * R_TOTAL + rbase + ln31];
      float v1 = x0t[(size_t)(s * 16 + q2 * 8 + 2 * r + 1) * R_TOTAL + rbase + ln31];
      Ah[s].u[r] = pack_trunc(v0, v1);
      float h0 = __uint_as_float(__float_as_uint(v0) & 0xffff0000u);
      float h1 = __uint_as_float(__float_as_uint(v1) & 0xffff0000u);
      Al[s].u[r] = pack_trunc(v0 - h0, v1 - h1);
    }
  }

  f32x16 acc;
  #pragma unroll
  for (int i = 0; i < 16; ++i) acc[i] = 0.f;
  const f32x16 zf = acc;              // zero C-operand bank

  // this wave's K-half units: sub-k sk = h*2+s at wq + h*4096 + s*512
  const u32* wq = wt + (((size_t)(kq * HKW) * 4 + nq) * 2) * 512;
  stage2k(wq, mybuf, lane);

  #pragma unroll 1
  for (int h = 0; h < HKW; ++h) {
    const int sk = 2 * h;
    const float* xlrow = xt + (size_t)(kq * HKW + h) * R_TOTAL + rbase + 4 * q2;

    // ---- sub-k 0 ----
    __builtin_amdgcn_s_waitcnt(0x0F70);   // vmcnt(0): unit sk ready
    const u32* buf0 = mybuf + (sk & 1) * 512;
    PackB bh0, bl0;
    bh0.v = *(const u32x4*)(buf0 + q2 * 128 + ln31 * 4);
    bl0.v = *(const u32x4*)(buf0 + 256 + q2 * 128 + ln31 * 4);
    stage2k(wq + (size_t)((sk + 1) >> 1) * 4096 + (size_t)((sk + 1) & 1) * 512,
            mybuf + (1 - (sk & 1)) * 512, lane);
    f32x4 xq[4];                          // xl broadcasts, overlap MFMA chain
    #pragma unroll
    for (int g = 0; g < 4; ++g) xq[g] = *(const f32x4*)(xlrow + 8 * g);

    f32x16 Y;
    Y = __builtin_amdgcn_mfma_f32_32x32x16_bf16(Ah[0].s, bh0.s, zf, 0, 0, 0);
    Y = __builtin_amdgcn_mfma_f32_32x32x16_bf16(Ah[0].s, bl0.s, Y, 0, 0, 0);
    Y = __builtin_amdgcn_mfma_f32_32x32x16_bf16(Al[0].s, bh0.s, Y, 0, 0, 0);

    // ---- sub-k 1 ----
    __builtin_amdgcn_s_waitcnt(0x0F70);   // vmcnt(0): unit sk+1 ready
    const u32* buf1 = mybuf + ((sk + 1) & 1) * 512;
    PackB bh1, bl1;
    bh1.v = *(const u32x4*)(buf1 + q2 * 128 + ln31 * 4);
    bl1.v = *(const u32x4*)(buf1 + 256 + q2 * 128 + ln31 * 4);
    if (sk + 2 < 2 * HKW)
      stage2k(wq + (size_t)((sk + 2) >> 1) * 4096 + (size_t)((sk + 2) & 1) * 512,
              mybuf + (sk & 1) * 512, lane);

    Y = __builtin_amdgcn_mfma_f32_32x32x16_bf16(Ah[1].s, bh1.s, Y, 0, 0, 0);
    Y = __builtin_amdgcn_mfma_f32_32x32x16_bf16(Ah[1].s, bl1.s, Y, 0, 0, 0);
    Y = __builtin_amdgcn_mfma_f32_32x32x16_bf16(Al[1].s, bh1.s, Y, 0, 0, 0);

    // ---- fold: acc[4g+j] += xl[row 8g+j+4q2] * Y[4g+j]  (fp32 exact) ----
    #pragma unroll
    for (int g = 0; g < 4; ++g) {
      acc[4 * g + 0] += xq[g].x * Y[4 * g + 0];
      acc[4 * g + 1] += xq[g].y * Y[4 * g + 1];
      acc[4 * g + 2] += xq[g].z * Y[4 * g + 2];
      acc[4 * g + 3] += xq[g].w * Y[4 * g + 3];
    }
  }

  // ---------------- epilogue: kq-pair reduction + bias/relu/osum/store -------
  // Regions: (rt*2+nh) -> 1024 u32 each (4 regions, 16 KB of smem reused).
  __syncthreads();
  if (kq == 1) {
    u32* reg = smem + ((size_t)(rt * 2 + nh)) * 1024;
    #pragma unroll
    for (int g = 0; g < 4; ++g)
      *(f32x4*)(reg + ((size_t)g * 64 + lane) * 4) =
          f32x4{acc[4 * g + 0], acc[4 * g + 1], acc[4 * g + 2], acc[4 * g + 3]};
  }
  __syncthreads();
  if (kq == 0) {
    const u32* reg = smem + ((size_t)(rt * 2 + nh)) * 1024;
    const float bs = bias[nq * 32 + ln31];
    #pragma unroll
    for (int g = 0; g < 4; ++g) {
      f32x4 part = *(const f32x4*)(reg + ((size_t)g * 64 + lane) * 4);
      acc[4 * g + 0] += part.x; acc[4 * g + 1] += part.y;
      acc[4 * g + 2] += part.z; acc[4 * g + 3] += part.w;
    }
    #pragma unroll
    for (int i = 0; i < 16; ++i) {
      float v = acc[i] + bs;
      if (RELU) v = fmaxf(v, 0.f);
      acc[i] = v;
    }
    // d-sum: regs 0..7 -> batch (rbase>>4), regs 8..15 -> +1 (16 rows each)
    float s0 = 0.f, s1 = 0.f;
    #pragma unroll
    for (int i = 0; i < 8; ++i) { s0 += acc[i]; s1 += acc[8 + i]; }
    s0 += __shfl_xor(s0, 32, 64);
    s1 += __shfl_xor(s1, 32, 64);
    const int col = nq * 32 + ln31;
    if (q2 == 0) {
      osum[(size_t)((rbase >> 4) + 0) * 384 + col] = s0;
      osum[(size_t)((rbase >> 4) + 1) * 384 + col] = s1;
    }
    if (STORE_X) {
      #pragma unroll
      for (int g = 0; g < 4; ++g)
        *(f32x4*)&xoutT[(size_t)col * R_TOTAL + rbase + 8 * g + 4 * q2] =
            f32x4{acc[4 * g + 0], acc[4 * g + 1], acc[4 * g + 2], acc[4 * g + 3]};
    }
  }
}

extern "C" void kernel_launch(void* const* d_in, const int* in_sizes, int n_in,
                              void* d_out, int out_size, void* d_ws, size_t ws_size,
                              hipStream_t stream) {
  const float* in = (const float*)d_in[0];
  const float* W0 = (const float*)d_in[1];
  const float* b0 = (const float*)d_in[2];
  const float* W1 = (const float*)d_in[3];
  const float* b1 = (const float*)d_in[4];
  const float* W2 = (const float*)d_in[5];
  const float* b2 = (const float*)d_in[6];
  float* out = (float*)d_out;

  float* X0T = (float*)d_ws;                         // 32 x 16384   (2 MB)
  float* X1T = X0T + (size_t)32 * R_TOTAL;           // 128 x 16384  (8 MB)
  float* X2T = X1T + (size_t)128 * R_TOTAL;          // 128 x 16384  (8 MB)
  u32* Wt0 = (u32*)(X2T + (size_t)128 * R_TOTAL);    // 32*8*512 u32   (0.5 MB)
  u32* Wt1 = Wt0 + (size_t)32 * 8 * 512;             // 128*8*512 u32  (2 MB)
  u32* Wt2 = Wt1 + (size_t)128 * 8 * 512;            // 128*8*512 u32  (2 MB)
  // total ws: 22.5 MB

  build_x0t<<<128, 256, 0, stream>>>(in, X0T);
  swizzle_w<<<32, 256, 0, stream>>>(W0, Wt0);
  swizzle_w<<<128, 256, 0, stream>>>(W1, Wt1);
  swizzle_w<<<128, 256, 0, stream>>>(W2, Wt2);

  layer_mfma<32, true, true><<<512, 512, 0, stream>>>(X0T, X0T, Wt0, b0, X1T, out + 0);
  layer_mfma<128, true, true><<<512, 512, 0, stream>>>(X1T, X0T, Wt1, b1, X2T, out + 128);
  layer_mfma<128, false, false><<<512, 512, 0, stream>>>(X2T, X0T, Wt2, b2, nullptr, out + 256);
}